// Round 5
// baseline (134.664 us; speedup 1.0000x reference)
//
#include <hip/hip_runtime.h>
#include <math.h>

#define BB 4
#define NN 4096
#define MM 4096
#define TI 128
#define TJ 128
#define NTI (NN / TI)   // 32
#define NTJ (MM / TJ)   // 32

#define L2E100 144.26950408889634f   // 100*log2(e); exp(-100 d) = exp2(-L2E100 d)

// workspace layout (floats):
// [0,16384)      m2_row  (min d^2 over j, per (b,i))  -- float bits, used as uint
// [16384,32768)  m2_col  (min d^2 over i, per (b,j))
// [32768,49152)  num_r
// [49152,65536)  den_r
// [65536,81920)  num_c
// [81920,98304)  den_c

// DPP 16-lane-row reductions: row_shr:1/2/4/8 chain, full sum/min lands in
// lane 15 of each 16-lane row. Pure VALU (no LDS), ~4cyc latency per step —
// replaces __shfl_xor (~5 ops each: addr VALU + ds_bpermute + lgkm wait).
__device__ __forceinline__ float dpp_sum16(float v) {
    float t;
    t = __int_as_float(__builtin_amdgcn_update_dpp(0, __float_as_int(v), 0x111, 0xF, 0xF, true)); v += t;
    t = __int_as_float(__builtin_amdgcn_update_dpp(0, __float_as_int(v), 0x112, 0xF, 0xF, true)); v += t;
    t = __int_as_float(__builtin_amdgcn_update_dpp(0, __float_as_int(v), 0x114, 0xF, 0xF, true)); v += t;
    t = __int_as_float(__builtin_amdgcn_update_dpp(0, __float_as_int(v), 0x118, 0xF, 0xF, true)); v += t;
    return v;  // valid in lane (tx==15)
}
__device__ __forceinline__ float dpp_min16(float v) {
    float t;  // bound_ctrl=false + old=v: invalid-source lanes keep v (min-neutral)
    t = __int_as_float(__builtin_amdgcn_update_dpp(__float_as_int(v), __float_as_int(v), 0x111, 0xF, 0xF, false)); v = fminf(v, t);
    t = __int_as_float(__builtin_amdgcn_update_dpp(__float_as_int(v), __float_as_int(v), 0x112, 0xF, 0xF, false)); v = fminf(v, t);
    t = __int_as_float(__builtin_amdgcn_update_dpp(__float_as_int(v), __float_as_int(v), 0x114, 0xF, 0xF, false)); v = fminf(v, t);
    t = __int_as_float(__builtin_amdgcn_update_dpp(__float_as_int(v), __float_as_int(v), 0x118, 0xF, 0xF, false)); v = fminf(v, t);
    return v;  // valid in lane (tx==15)
}

__global__ __launch_bounds__(256)
void init_ws_kernel(float* ws, float* out) {
    int idx = blockIdx.x * 256 + threadIdx.x;
    if (idx < 2 * 16384) ws[idx] = 1e30f;
    else if (idx < 6 * 16384) ws[idx] = 0.0f;
    if (idx == 0) out[0] = 0.0f;
}

// Staging helper: xs4 = (-2x, |x|^2), ys4 = (y, |y|^2); d2 computed with the
// IDENTICAL fma chain in pass1 and pass2 so pass2's (d - m) <= 0 holds bitwise.
__device__ __forceinline__ float4 stage_x(const float* p) {
    float a = p[0], b = p[1], c = p[2];
    float4 r; r.x = -2.0f * a; r.y = -2.0f * b; r.z = -2.0f * c;
    r.w = fmaf(a, a, fmaf(b, b, c * c));
    return r;
}
__device__ __forceinline__ float4 stage_y(const float* p) {
    float a = p[0], b = p[1], c = p[2];
    float4 r; r.x = a; r.y = b; r.z = c;
    r.w = fmaf(a, a, fmaf(b, b, c * c));
    return r;
}
__device__ __forceinline__ float pair_d2(float4 X, float4 Y) {
    float pq = X.w + Y.w;
    float d2 = fmaf(X.x, Y.x, fmaf(X.y, Y.y, fmaf(X.z, Y.z, pq)));
    return fmaxf(d2, 0.0f);
}

// amdgpu_waves_per_eu(2,4): sets backend TARGET occupancy to 4 waves/EU ->
// register budget 128 VGPR. launch_bounds caps alone don't move the
// scheduler's pressure target (R3/R4: stuck at 56 VGPR, sink/spill in loop).
__global__ __launch_bounds__(256) __attribute__((amdgpu_waves_per_eu(2, 4)))
void pass1_min(const float* __restrict__ x, const float* __restrict__ y,
               unsigned int* __restrict__ m2_row, unsigned int* __restrict__ m2_col) {
    const int bid = blockIdx.x;
    const int b   = bid / (NTI * NTJ);
    const int rem = bid % (NTI * NTJ);
    const int i0  = (rem / NTJ) * TI;
    const int j0  = (rem % NTJ) * TJ;

    __shared__ float4 xs4[TI];
    __shared__ float4 ys4[TJ];
    __shared__ unsigned int cmin_s[TJ];

    const int t = threadIdx.x;
    if (t < TI) {
        xs4[t] = stage_x(&x[(size_t)(b * NN + i0 + t) * 3]);
        cmin_s[t] = 0x7F7FFFFFu;  // FLT_MAX bits
    } else {
        int j = t - TI;
        ys4[j] = stage_y(&y[(size_t)(b * MM + j0 + j) * 3]);
    }
    __syncthreads();

    const int tx = t & 15, ty = t >> 4;
    float4 Y[8]; float cmin[8];
#pragma unroll
    for (int l = 0; l < 8; ++l) { Y[l] = ys4[tx + l * 16]; cmin[l] = 1e30f; }

#pragma unroll
    for (int k = 0; k < 8; ++k) {
        float4 X = xs4[ty + k * 16];
        float rmin = 1e30f;
#pragma unroll
        for (int l = 0; l < 8; ++l) {
            float d2 = pair_d2(X, Y[l]);
            rmin = fminf(rmin, d2);
            cmin[l] = fminf(cmin[l], d2);
        }
        rmin = dpp_min16(rmin);
        if (tx == 15) atomicMin(&m2_row[b * NN + i0 + ty + k * 16], __float_as_uint(rmin));
    }
    // cols: per-lane LDS atomicMin (4-way same-address within wave; no shuffles)
#pragma unroll
    for (int l = 0; l < 8; ++l)
        atomicMin(&cmin_s[tx + l * 16], __float_as_uint(cmin[l]));
    __syncthreads();
    if (t < TJ) atomicMin(&m2_col[b * MM + j0 + t], cmin_s[t]);
}

__global__ __launch_bounds__(256) __attribute__((amdgpu_waves_per_eu(2, 4)))
void pass2_acc(const float* __restrict__ x, const float* __restrict__ y,
               const unsigned int* __restrict__ m2_row, const unsigned int* __restrict__ m2_col,
               float* __restrict__ num_r, float* __restrict__ den_r,
               float* __restrict__ num_c, float* __restrict__ den_c) {
    const int bid = blockIdx.x;
    const int b   = bid / (NTI * NTJ);
    const int rem = bid % (NTI * NTJ);
    const int i0  = (rem / NTJ) * TI;
    const int j0  = (rem % NTJ) * TJ;

    __shared__ float4 xs4[TI];
    __shared__ float4 ys4[TJ];
    __shared__ float ar[TI];   // L2E100 * sqrt(m2_row)
    __shared__ float ac[TJ];
    __shared__ float snc[TJ], sdc[TJ];

    const int t = threadIdx.x;
    if (t < TI) {
        xs4[t] = stage_x(&x[(size_t)(b * NN + i0 + t) * 3]);
        ar[t]  = L2E100 * __builtin_amdgcn_sqrtf(__uint_as_float(m2_row[b * NN + i0 + t]));
        snc[t] = 0.0f; sdc[t] = 0.0f;
    } else {
        int j = t - TI;
        ys4[j] = stage_y(&y[(size_t)(b * MM + j0 + j) * 3]);
        ac[j]  = L2E100 * __builtin_amdgcn_sqrtf(__uint_as_float(m2_col[b * MM + j0 + j]));
    }
    __syncthreads();

    const int tx = t & 15, ty = t >> 4;
    float4 Y[8]; float sc[8], nc[8], dc[8];
#pragma unroll
    for (int l = 0; l < 8; ++l) {
        Y[l] = ys4[tx + l * 16]; sc[l] = ac[tx + l * 16];
        nc[l] = 0.0f; dc[l] = 0.0f;
    }

#pragma unroll
    for (int k = 0; k < 8; ++k) {
        float4 X = xs4[ty + k * 16];
        float srk = ar[ty + k * 16];
        float nr = 0.0f, dr = 0.0f;
#pragma unroll
        for (int l = 0; l < 8; ++l) {
            float d2 = pair_d2(X, Y[l]);
            float d  = __builtin_amdgcn_sqrtf(d2);                        // v_sqrt_f32
            float er = __builtin_amdgcn_exp2f(fmaf(d, -L2E100, srk));     // v_exp_f32
            float ec = __builtin_amdgcn_exp2f(fmaf(d, -L2E100, sc[l]));
            nr = fmaf(d, er, nr);  dr += er;
            nc[l] = fmaf(d, ec, nc[l]);  dc[l] += ec;
        }
        // row k reduce across the 16 tx lanes (pure-VALU DPP), one atomic lane
        float vn = dpp_sum16(nr);
        float vd = dpp_sum16(dr);
        if (tx == 15) {
            atomicAdd(&num_r[b * NN + i0 + ty + k * 16], vn);
            atomicAdd(&den_r[b * NN + i0 + ty + k * 16], vd);
        }
    }
    // cols: per-lane LDS atomicAdd (4-way same-address), then one global per col
#pragma unroll
    for (int l = 0; l < 8; ++l) {
        atomicAdd(&snc[tx + l * 16], nc[l]);
        atomicAdd(&sdc[tx + l * 16], dc[l]);
    }
    __syncthreads();
    if (t < TJ) {
        atomicAdd(&num_c[b * MM + j0 + t], snc[t]);
        atomicAdd(&den_c[b * MM + j0 + t], sdc[t]);
    }
}

__global__ __launch_bounds__(256)
void finalize_kernel(const float* __restrict__ num_r, const float* __restrict__ den_r,
                     const float* __restrict__ num_c, const float* __restrict__ den_c,
                     float* __restrict__ out) {
    const int gid = blockIdx.x * 256 + threadIdx.x;
    float s = 0.0f;
    for (int idx = gid; idx < BB * NN; idx += 32 * 256) {
        s = fmaf(num_r[idx], __builtin_amdgcn_rcpf(den_r[idx]), s);
        s = fmaf(num_c[idx], __builtin_amdgcn_rcpf(den_c[idx]), s);
    }
#pragma unroll
    for (int m = 1; m < 64; m <<= 1) s += __shfl_xor(s, m);
    __shared__ float wsum[4];
    const int t = threadIdx.x;
    if ((t & 63) == 0) wsum[t >> 6] = s;
    __syncthreads();
    if (t == 0) {
        float v = (wsum[0] + wsum[1] + wsum[2] + wsum[3]) * (1.0f / (float)(BB * NN));
        atomicAdd(out, v);
    }
}

extern "C" void kernel_launch(void* const* d_in, const int* in_sizes, int n_in,
                              void* d_out, int out_size, void* d_ws, size_t ws_size,
                              hipStream_t stream) {
    const float* x = (const float*)d_in[0];
    const float* y = (const float*)d_in[1];
    float* ws = (float*)d_ws;

    unsigned int* m2_row = (unsigned int*)(ws);
    unsigned int* m2_col = (unsigned int*)(ws + 16384);
    float* num_r = ws + 32768;
    float* den_r = ws + 49152;
    float* num_c = ws + 65536;
    float* den_c = ws + 81920;

    hipLaunchKernelGGL(init_ws_kernel, dim3(384), dim3(256), 0, stream, ws, (float*)d_out);
    dim3 grid(BB * NTI * NTJ);  // 4096 blocks
    hipLaunchKernelGGL(pass1_min, grid, dim3(256), 0, stream, x, y, m2_row, m2_col);
    hipLaunchKernelGGL(pass2_acc, grid, dim3(256), 0, stream,
                       x, y, m2_row, m2_col, num_r, den_r, num_c, den_c);
    hipLaunchKernelGGL(finalize_kernel, dim3(32), dim3(256), 0, stream,
                       num_r, den_r, num_c, den_c, (float*)d_out);
}

// Round 6
// 68.710 us; speedup vs baseline: 1.9599x; 1.9599x over previous
//
#include <hip/hip_runtime.h>
#include <math.h>

#define BB 4
#define NN 4096
#define MM 4096
#define TI 128
#define TJ 128
#define NTI (NN / TI)   // 32
#define NTJ (MM / TJ)   // 32

#define L2E100 144.26950408889634f   // 100*log2(e); exp(-100 d) = exp2(-L2E100 d)

// ---------- cross-lane helpers ----------
// DPP 16-lane-row sum: row_shr chain; full sum lands in lane (tx==15).
__device__ __forceinline__ float dpp_sum16(float v) {
    float t;
    t = __int_as_float(__builtin_amdgcn_update_dpp(0, __float_as_int(v), 0x111, 0xF, 0xF, true)); v += t;
    t = __int_as_float(__builtin_amdgcn_update_dpp(0, __float_as_int(v), 0x112, 0xF, 0xF, true)); v += t;
    t = __int_as_float(__builtin_amdgcn_update_dpp(0, __float_as_int(v), 0x114, 0xF, 0xF, true)); v += t;
    t = __int_as_float(__builtin_amdgcn_update_dpp(0, __float_as_int(v), 0x118, 0xF, 0xF, true)); v += t;
    return v;
}
__device__ __forceinline__ float dpp_min16(float v) {
    float t;
    t = __int_as_float(__builtin_amdgcn_update_dpp(__float_as_int(v), __float_as_int(v), 0x111, 0xF, 0xF, false)); v = fminf(v, t);
    t = __int_as_float(__builtin_amdgcn_update_dpp(__float_as_int(v), __float_as_int(v), 0x112, 0xF, 0xF, false)); v = fminf(v, t);
    t = __int_as_float(__builtin_amdgcn_update_dpp(__float_as_int(v), __float_as_int(v), 0x114, 0xF, 0xF, false)); v = fminf(v, t);
    t = __int_as_float(__builtin_amdgcn_update_dpp(__float_as_int(v), __float_as_int(v), 0x118, 0xF, 0xF, false)); v = fminf(v, t);
    return v;
}
__device__ __forceinline__ float bperm(float v, int addr) {
    return __int_as_float(__builtin_amdgcn_ds_bpermute(addr, __float_as_int(v)));
}

// ---------- staging: X=(-2x,|x|^2), Y=(y,|y|^2); d2 = X.Y + (Xw+Yw) ----------
__device__ __forceinline__ float4 stage_x(const float* p) {
    float a = p[0], b = p[1], c = p[2];
    float4 r; r.x = -2.0f * a; r.y = -2.0f * b; r.z = -2.0f * c;
    r.w = fmaf(a, a, fmaf(b, b, c * c));
    return r;
}
__device__ __forceinline__ float4 stage_y(const float* p) {
    float a = p[0], b = p[1], c = p[2];
    float4 r; r.x = a; r.y = b; r.z = c;
    r.w = fmaf(a, a, fmaf(b, b, c * c));
    return r;
}

// ---------- hand-scheduled inner loops (2 pairs per block, 2 ILP chains) ----------
// pass1: 10 instr / 2 pairs. pq* enter holding Xw+Yw*.
__device__ __forceinline__ void p1_pair2(
    float pqA, float pqB, float Xx, float Xy, float Xz,
    float YxA, float YyA, float YzA, float YxB, float YyB, float YzB,
    float& rmin, float& cminA, float& cminB)
{
    asm("v_fmac_f32 %[pqA], %[Xz], %[YzA]\n\t"
        "v_fmac_f32 %[pqB], %[Xz], %[YzB]\n\t"
        "v_fmac_f32 %[pqA], %[Xy], %[YyA]\n\t"
        "v_fmac_f32 %[pqB], %[Xy], %[YyB]\n\t"
        "v_fmac_f32 %[pqA], %[Xx], %[YxA]\n\t"
        "v_fmac_f32 %[pqB], %[Xx], %[YxB]\n\t"
        "v_min_f32 %[rmin], %[rmin], %[pqA]\n\t"
        "v_min_f32 %[cminA], %[cminA], %[pqA]\n\t"
        "v_min_f32 %[rmin], %[rmin], %[pqB]\n\t"
        "v_min_f32 %[cminB], %[cminB], %[pqB]"
        : [pqA]"+v"(pqA), [pqB]"+v"(pqB), [rmin]"+v"(rmin),
          [cminA]"+v"(cminA), [cminB]"+v"(cminB)
        : [Xx]"v"(Xx), [Xy]"v"(Xy), [Xz]"v"(Xz),
          [YxA]"v"(YxA), [YyA]"v"(YyA), [YzA]"v"(YzA),
          [YxB]"v"(YxB), [YyB]"v"(YyB), [YzB]"v"(YzB));
}

// pass2: 26 instr / 2 pairs = 20 VALU + 6 trans.
__device__ __forceinline__ void p2_pair2(
    float pqA, float pqB, float Xx, float Xy, float Xz, float srk,
    float YxA, float YyA, float YzA, float scA,
    float YxB, float YyB, float YzB, float scB,
    float nL,
    float& nr, float& dr, float& ncA, float& dcA, float& ncB, float& dcB)
{
    float dA, dB, eA, eB;
    asm("v_fmac_f32 %[pqA], %[Xz], %[YzA]\n\t"
        "v_fmac_f32 %[pqB], %[Xz], %[YzB]\n\t"
        "v_fmac_f32 %[pqA], %[Xy], %[YyA]\n\t"
        "v_fmac_f32 %[pqB], %[Xy], %[YyB]\n\t"
        "v_fmac_f32 %[pqA], %[Xx], %[YxA]\n\t"
        "v_fmac_f32 %[pqB], %[Xx], %[YxB]\n\t"
        "v_max_f32 %[pqA], 0, %[pqA]\n\t"
        "v_max_f32 %[pqB], 0, %[pqB]\n\t"
        "v_sqrt_f32 %[dA], %[pqA]\n\t"
        "v_sqrt_f32 %[dB], %[pqB]\n\t"
        "v_fma_f32 %[eA], %[dA], %[nL], %[srk]\n\t"
        "v_fma_f32 %[eB], %[dB], %[nL], %[srk]\n\t"
        "v_exp_f32 %[eA], %[eA]\n\t"
        "v_exp_f32 %[eB], %[eB]\n\t"
        "v_fmac_f32 %[nr], %[dA], %[eA]\n\t"
        "v_add_f32 %[dr], %[dr], %[eA]\n\t"
        "v_fmac_f32 %[nr], %[dB], %[eB]\n\t"
        "v_add_f32 %[dr], %[dr], %[eB]\n\t"
        "v_fma_f32 %[eA], %[dA], %[nL], %[scA]\n\t"
        "v_fma_f32 %[eB], %[dB], %[nL], %[scB]\n\t"
        "v_exp_f32 %[eA], %[eA]\n\t"
        "v_exp_f32 %[eB], %[eB]\n\t"
        "v_fmac_f32 %[ncA], %[dA], %[eA]\n\t"
        "v_add_f32 %[dcA], %[dcA], %[eA]\n\t"
        "v_fmac_f32 %[ncB], %[dB], %[eB]\n\t"
        "v_add_f32 %[dcB], %[dcB], %[eB]"
        : [pqA]"+v"(pqA), [pqB]"+v"(pqB),
          [nr]"+v"(nr), [dr]"+v"(dr),
          [ncA]"+v"(ncA), [dcA]"+v"(dcA), [ncB]"+v"(ncB), [dcB]"+v"(dcB),
          [dA]"=&v"(dA), [dB]"=&v"(dB), [eA]"=&v"(eA), [eB]"=&v"(eB)
        : [Xx]"v"(Xx), [Xy]"v"(Xy), [Xz]"v"(Xz), [srk]"v"(srk),
          [YxA]"v"(YxA), [YyA]"v"(YyA), [YzA]"v"(YzA), [scA]"v"(scA),
          [YxB]"v"(YxB), [YyB]"v"(YyB), [YzB]"v"(YzB), [scB]"v"(scB),
          [nL]"s"(nL));
}

// workspace layout (floats): see R1. m2_* stored as float bits (uint min ok:
// any sr bias cancels in num/den ratio, so approximate mins are harmless).
__global__ __launch_bounds__(256)
void init_ws_kernel(float* ws, float* out) {
    int idx = blockIdx.x * 256 + threadIdx.x;
    if (idx < 2 * 16384) ws[idx] = 1e30f;
    else if (idx < 6 * 16384) ws[idx] = 0.0f;
    if (idx == 0) out[0] = 0.0f;
}

__global__ __launch_bounds__(256)
void pass1_min(const float* __restrict__ x, const float* __restrict__ y,
               unsigned int* __restrict__ m2_row, unsigned int* __restrict__ m2_col) {
    const int bid = blockIdx.x;
    const int b   = bid / (NTI * NTJ);
    const int rem = bid % (NTI * NTJ);
    const int i0  = (rem / NTJ) * TI;
    const int j0  = (rem % NTJ) * TJ;

    __shared__ float4 xs4[TI];
    __shared__ float4 ys4[TJ];
    __shared__ float  cm_w[4][TJ];

    const int t = threadIdx.x;
    if (t < TI) xs4[t] = stage_x(&x[(size_t)(b * NN + i0 + t) * 3]);
    else        ys4[t - TI] = stage_y(&y[(size_t)(b * MM + j0 + (t - TI)) * 3]);
    __syncthreads();

    const int tx = t & 15, ty = t >> 4;
    const int lane = t & 63, wv = t >> 6;
    float4 Y[8]; float cmin[8];
#pragma unroll
    for (int l = 0; l < 8; ++l) { Y[l] = ys4[tx + l * 16]; cmin[l] = 1e30f; }

#pragma unroll
    for (int k = 0; k < 8; ++k) {
        float4 X = xs4[ty + k * 16];
        float rmin = 1e30f;
#pragma unroll
        for (int l = 0; l < 8; l += 2) {
            p1_pair2(X.w + Y[l].w, X.w + Y[l + 1].w, X.x, X.y, X.z,
                     Y[l].x, Y[l].y, Y[l].z, Y[l + 1].x, Y[l + 1].y, Y[l + 1].z,
                     rmin, cmin[l], cmin[l + 1]);
        }
        rmin = dpp_min16(rmin);
        if (tx == 15) atomicMin(&m2_row[b * NN + i0 + ty + k * 16], __float_as_uint(rmin));
    }

    // cols: butterfly across ty within wave (xor16, xor32), per-wave LDS slot,
    // then 4-way combine. No LDS atomics.
    const int a16 = (lane ^ 16) << 2, a32 = (lane ^ 32) << 2;
#pragma unroll
    for (int l = 0; l < 8; ++l) {
        float v = cmin[l];
        v = fminf(v, bperm(v, a16));
        v = fminf(v, bperm(v, a32));
        if (lane < 16) cm_w[wv][lane + l * 16] = v;
    }
    __syncthreads();
    if (t < TJ) {
        float m = fminf(fminf(cm_w[0][t], cm_w[1][t]), fminf(cm_w[2][t], cm_w[3][t]));
        atomicMin(&m2_col[b * MM + j0 + t], __float_as_uint(m));
    }
}

__global__ __launch_bounds__(256)
void pass2_acc(const float* __restrict__ x, const float* __restrict__ y,
               const unsigned int* __restrict__ m2_row, const unsigned int* __restrict__ m2_col,
               float* __restrict__ num_r, float* __restrict__ den_r,
               float* __restrict__ num_c, float* __restrict__ den_c) {
    const int bid = blockIdx.x;
    const int b   = bid / (NTI * NTJ);
    const int rem = bid % (NTI * NTJ);
    const int i0  = (rem / NTJ) * TI;
    const int j0  = (rem % NTJ) * TJ;

    __shared__ float4 xs4[TI];
    __shared__ float4 ys4[TJ];
    __shared__ float  ar[TI];
    __shared__ float  ac[TJ];
    __shared__ float  sn_w[4][TJ];
    __shared__ float  sd_w[4][TJ];

    const int t = threadIdx.x;
    if (t < TI) {
        xs4[t] = stage_x(&x[(size_t)(b * NN + i0 + t) * 3]);
        ar[t]  = L2E100 * __builtin_amdgcn_sqrtf(fmaxf(__uint_as_float(m2_row[b * NN + i0 + t]), 0.0f));
    } else {
        int j = t - TI;
        ys4[j] = stage_y(&y[(size_t)(b * MM + j0 + j) * 3]);
        ac[j]  = L2E100 * __builtin_amdgcn_sqrtf(fmaxf(__uint_as_float(m2_col[b * MM + j0 + j]), 0.0f));
    }
    __syncthreads();

    const int tx = t & 15, ty = t >> 4;
    const int lane = t & 63, wv = t >> 6;
    const float nL = -L2E100;

    float4 Y[8]; float sc[8], nc[8], dc[8];
#pragma unroll
    for (int l = 0; l < 8; ++l) {
        Y[l] = ys4[tx + l * 16]; sc[l] = ac[tx + l * 16];
        nc[l] = 0.0f; dc[l] = 0.0f;
    }

#pragma unroll
    for (int k = 0; k < 8; ++k) {
        float4 X = xs4[ty + k * 16];
        float srk = ar[ty + k * 16];
        float nr = 0.0f, dr = 0.0f;
#pragma unroll
        for (int l = 0; l < 8; l += 2) {
            p2_pair2(X.w + Y[l].w, X.w + Y[l + 1].w, X.x, X.y, X.z, srk,
                     Y[l].x, Y[l].y, Y[l].z, sc[l],
                     Y[l + 1].x, Y[l + 1].y, Y[l + 1].z, sc[l + 1], nL,
                     nr, dr, nc[l], dc[l], nc[l + 1], dc[l + 1]);
        }
        float vn = dpp_sum16(nr);
        float vd = dpp_sum16(dr);
        if (tx == 15) {
            atomicAdd(&num_r[b * NN + i0 + ty + k * 16], vn);
            atomicAdd(&den_r[b * NN + i0 + ty + k * 16], vd);
        }
    }

    // cols: butterfly xor16/xor32 within wave, per-wave LDS slot, 4-way combine.
    const int a16 = (lane ^ 16) << 2, a32 = (lane ^ 32) << 2;
#pragma unroll
    for (int l = 0; l < 8; ++l) {
        float vn = nc[l], vd = dc[l];
        vn += bperm(vn, a16); vd += bperm(vd, a16);
        vn += bperm(vn, a32); vd += bperm(vd, a32);
        if (lane < 16) { sn_w[wv][lane + l * 16] = vn; sd_w[wv][lane + l * 16] = vd; }
    }
    __syncthreads();
    if (t < TJ) {
        float ns = (sn_w[0][t] + sn_w[1][t]) + (sn_w[2][t] + sn_w[3][t]);
        float ds = (sd_w[0][t] + sd_w[1][t]) + (sd_w[2][t] + sd_w[3][t]);
        atomicAdd(&num_c[b * MM + j0 + t], ns);
        atomicAdd(&den_c[b * MM + j0 + t], ds);
    }
}

__global__ __launch_bounds__(256)
void finalize_kernel(const float* __restrict__ num_r, const float* __restrict__ den_r,
                     const float* __restrict__ num_c, const float* __restrict__ den_c,
                     float* __restrict__ out) {
    const int gid = blockIdx.x * 256 + threadIdx.x;
    float s = 0.0f;
    for (int idx = gid; idx < BB * NN; idx += 32 * 256) {
        s = fmaf(num_r[idx], __builtin_amdgcn_rcpf(den_r[idx]), s);
        s = fmaf(num_c[idx], __builtin_amdgcn_rcpf(den_c[idx]), s);
    }
#pragma unroll
    for (int m = 1; m < 64; m <<= 1) s += __shfl_xor(s, m);
    __shared__ float wsum[4];
    const int t = threadIdx.x;
    if ((t & 63) == 0) wsum[t >> 6] = s;
    __syncthreads();
    if (t == 0) {
        float v = (wsum[0] + wsum[1] + wsum[2] + wsum[3]) * (1.0f / (float)(BB * NN));
        atomicAdd(out, v);
    }
}

extern "C" void kernel_launch(void* const* d_in, const int* in_sizes, int n_in,
                              void* d_out, int out_size, void* d_ws, size_t ws_size,
                              hipStream_t stream) {
    const float* x = (const float*)d_in[0];
    const float* y = (const float*)d_in[1];
    float* ws = (float*)d_ws;

    unsigned int* m2_row = (unsigned int*)(ws);
    unsigned int* m2_col = (unsigned int*)(ws + 16384);
    float* num_r = ws + 32768;
    float* den_r = ws + 49152;
    float* num_c = ws + 65536;
    float* den_c = ws + 81920;

    hipLaunchKernelGGL(init_ws_kernel, dim3(384), dim3(256), 0, stream, ws, (float*)d_out);
    dim3 grid(BB * NTI * NTJ);  // 4096 blocks
    hipLaunchKernelGGL(pass1_min, grid, dim3(256), 0, stream, x, y, m2_row, m2_col);
    hipLaunchKernelGGL(pass2_acc, grid, dim3(256), 0, stream,
                       x, y, m2_row, m2_col, num_r, den_r, num_c, den_c);
    hipLaunchKernelGGL(finalize_kernel, dim3(32), dim3(256), 0, stream,
                       num_r, den_r, num_c, den_c, (float*)d_out);
}